// Round 1
// 699.512 us; speedup vs baseline: 1.0042x; 1.0042x over previous
//
#include <hip/hip_runtime.h>
#include <math.h>

#define N_NODES 100000
#define N_EDGES 1600000
#define IN_DIM 128
#define HEADS 8
#define D1 16
#define D2 8
#define NEG_SLOPE 0.2f

// ---------------------------------------------------------------------------
// Register-tiled GEMM (R5 structure, RPT x 8 tile).
// History: R5 (8x8, unroll 4, launch_bounds(256)) = 144 us, VGPR 84, NO
// spill — the only spill-free tiled variant. Its limit was latency:
// 782 blocks (3/CU), occupancy 21%, VALUBusy 16%.
// R10 change: RPT=4 halves per-thread state (acc 32 regs, in-flight 48) and
// doubles the grid (1563 blocks, ~6 blocks/CU, ~2x resident waves).
// Discipline (R8/R9 lessons): straight-line unrolled code, no lambdas, no
// address-taken arrays, modest unroll(2) — keep VGPR <= 96.
// ---------------------------------------------------------------------------
template<int K, int OUTC, int RPT>
__global__ __launch_bounds__(256)
void gemm_tile_kernel(const float* __restrict__ A, const float* __restrict__ W,
                      float* __restrict__ C, int n_rows) {
    constexpr int CT = OUTC / 8;       // col-threads per row group
    constexpr int RT = 256 / CT;       // row-threads
    constexpr int BM = RT * RPT;       // rows per block
    int tid = threadIdx.x;
    int ct = tid % CT;
    int rt = tid / CT;
    int row0 = blockIdx.x * BM + rt * RPT;
    int col0 = ct * 8;

    const float* ap[RPT];
#pragma unroll
    for (int r = 0; r < RPT; ++r) {
        int rr = row0 + r;
        rr = rr < n_rows ? rr : n_rows - 1;   // clamp: keep address valid
        ap[r] = A + (long)rr * K;
    }

    float4 acc[RPT][2];
#pragma unroll
    for (int r = 0; r < RPT; ++r) {
        acc[r][0] = make_float4(0.f, 0.f, 0.f, 0.f);
        acc[r][1] = make_float4(0.f, 0.f, 0.f, 0.f);
    }

    const float* wp = W + col0;
#pragma unroll 2
    for (int c4 = 0; c4 < K / 4; ++c4) {
        float4 a[RPT];
#pragma unroll
        for (int r = 0; r < RPT; ++r) a[r] = *(const float4*)(ap[r] + c4 * 4);
        float4 w0[4], w1[4];
#pragma unroll
        for (int k = 0; k < 4; ++k) {
            const float* wk = wp + (c4 * 4 + k) * OUTC;
            w0[k] = *(const float4*)(wk);
            w1[k] = *(const float4*)(wk + 4);
        }
#pragma unroll
        for (int r = 0; r < RPT; ++r) {
            float a0 = a[r].x, a1 = a[r].y, a2 = a[r].z, a3 = a[r].w;
            acc[r][0].x = fmaf(a0, w0[0].x, acc[r][0].x);
            acc[r][0].y = fmaf(a0, w0[0].y, acc[r][0].y);
            acc[r][0].z = fmaf(a0, w0[0].z, acc[r][0].z);
            acc[r][0].w = fmaf(a0, w0[0].w, acc[r][0].w);
            acc[r][1].x = fmaf(a0, w1[0].x, acc[r][1].x);
            acc[r][1].y = fmaf(a0, w1[0].y, acc[r][1].y);
            acc[r][1].z = fmaf(a0, w1[0].z, acc[r][1].z);
            acc[r][1].w = fmaf(a0, w1[0].w, acc[r][1].w);
            acc[r][0].x = fmaf(a1, w0[1].x, acc[r][0].x);
            acc[r][0].y = fmaf(a1, w0[1].y, acc[r][0].y);
            acc[r][0].z = fmaf(a1, w0[1].z, acc[r][0].z);
            acc[r][0].w = fmaf(a1, w0[1].w, acc[r][0].w);
            acc[r][1].x = fmaf(a1, w1[1].x, acc[r][1].x);
            acc[r][1].y = fmaf(a1, w1[1].y, acc[r][1].y);
            acc[r][1].z = fmaf(a1, w1[1].z, acc[r][1].z);
            acc[r][1].w = fmaf(a1, w1[1].w, acc[r][1].w);
            acc[r][0].x = fmaf(a2, w0[2].x, acc[r][0].x);
            acc[r][0].y = fmaf(a2, w0[2].y, acc[r][0].y);
            acc[r][0].z = fmaf(a2, w0[2].z, acc[r][0].z);
            acc[r][0].w = fmaf(a2, w0[2].w, acc[r][0].w);
            acc[r][1].x = fmaf(a2, w1[2].x, acc[r][1].x);
            acc[r][1].y = fmaf(a2, w1[2].y, acc[r][1].y);
            acc[r][1].z = fmaf(a2, w1[2].z, acc[r][1].z);
            acc[r][1].w = fmaf(a2, w1[2].w, acc[r][1].w);
            acc[r][0].x = fmaf(a3, w0[3].x, acc[r][0].x);
            acc[r][0].y = fmaf(a3, w0[3].y, acc[r][0].y);
            acc[r][0].z = fmaf(a3, w0[3].z, acc[r][0].z);
            acc[r][0].w = fmaf(a3, w0[3].w, acc[r][0].w);
            acc[r][1].x = fmaf(a3, w1[3].x, acc[r][1].x);
            acc[r][1].y = fmaf(a3, w1[3].y, acc[r][1].y);
            acc[r][1].z = fmaf(a3, w1[3].z, acc[r][1].z);
            acc[r][1].w = fmaf(a3, w1[3].w, acc[r][1].w);
        }
    }

#pragma unroll
    for (int r = 0; r < RPT; ++r) {
        int rr = row0 + r;
        if (rr < n_rows) {
            float* cp = C + (long)rr * OUTC + col0;
            *(float4*)(cp)     = acc[r][0];
            *(float4*)(cp + 4) = acc[r][1];
        }
    }
}

// ---------------------------------------------------------------------------
// Attention scores: one thread per (node, head); float4 loads of the D-vec.
// ---------------------------------------------------------------------------
template<int D>
__global__ void scores_kernel(const float* __restrict__ h,
                              const float* __restrict__ a_src,
                              const float* __restrict__ a_dst,
                              float* __restrict__ s_src,
                              float* __restrict__ s_dst) {
    int i = blockIdx.x * blockDim.x + threadIdx.x;   // over N_NODES*HEADS
    if (i >= N_NODES * HEADS) return;
    int hd = i & 7;
    const float4* hp = (const float4*)(h + (long)i * D);
    const float4* as = (const float4*)(a_src + hd * D);
    const float4* ad = (const float4*)(a_dst + hd * D);
    float ss = 0.f, sd = 0.f;
#pragma unroll
    for (int r = 0; r < D / 4; ++r) {
        float4 v = hp[r], s4 = as[r], d4 = ad[r];
        ss = fmaf(v.x, s4.x, ss); ss = fmaf(v.y, s4.y, ss);
        ss = fmaf(v.z, s4.z, ss); ss = fmaf(v.w, s4.w, ss);
        sd = fmaf(v.x, d4.x, sd); sd = fmaf(v.y, d4.y, sd);
        sd = fmaf(v.z, d4.z, sd); sd = fmaf(v.w, d4.w, sd);
    }
    s_src[i] = ss;
    s_dst[i] = sd;
}

// ---------------------------------------------------------------------------
// CSR build: count -> block scan -> scan of block sums -> add offsets -> scatter
// ---------------------------------------------------------------------------
__global__ void count_kernel(const int* __restrict__ dst, int* __restrict__ counts) {
    int e = blockIdx.x * blockDim.x + threadIdx.x;
    if (e < N_EDGES) atomicAdd(&counts[dst[e]], 1);
}

__global__ void scan_block_kernel(const int* __restrict__ counts, int* __restrict__ rs,
                                  int* __restrict__ bsums, int n) {
    __shared__ int sh[256];
    int tid = threadIdx.x;
    int base = blockIdx.x * 1024 + tid * 4;
    int c0 = (base + 0 < n) ? counts[base + 0] : 0;
    int c1 = (base + 1 < n) ? counts[base + 1] : 0;
    int c2 = (base + 2 < n) ? counts[base + 2] : 0;
    int c3 = (base + 3 < n) ? counts[base + 3] : 0;
    int p1 = c0, p2 = c0 + c1, p3 = c0 + c1 + c2, tot = c0 + c1 + c2 + c3;
    sh[tid] = tot;
    __syncthreads();
    int run = tot;
    for (int off = 1; off < 256; off <<= 1) {
        int add = (tid >= off) ? sh[tid - off] : 0;
        __syncthreads();
        run += add;
        sh[tid] = run;
        __syncthreads();
    }
    int excl = run - tot;
    if (base + 0 < n) rs[base + 0] = excl;
    if (base + 1 < n) rs[base + 1] = excl + p1;
    if (base + 2 < n) rs[base + 2] = excl + p2;
    if (base + 3 < n) rs[base + 3] = excl + p3;
    if (tid == 255) bsums[blockIdx.x] = run;   // block total
}

__global__ void scan_sums_kernel(int* __restrict__ bsums, int nb) {
    if (blockIdx.x == 0 && threadIdx.x == 0) {
        int run = 0;
        for (int i = 0; i < nb; ++i) { int c = bsums[i]; bsums[i] = run; run += c; }
    }
}

__global__ void add_offsets_kernel(int* __restrict__ rs, const int* __restrict__ bsums,
                                   int* __restrict__ cursor, int n) {
    int tid = threadIdx.x;
    int base = blockIdx.x * 1024 + tid * 4;
    int add = bsums[blockIdx.x];
#pragma unroll
    for (int j = 0; j < 4; ++j) {
        int i = base + j;
        if (i < n) { int v = rs[i] + add; rs[i] = v; cursor[i] = v; }
    }
    if (blockIdx.x == 0 && tid == 0) rs[n] = N_EDGES;
}

__global__ void scatter_kernel(const int* __restrict__ src, const int* __restrict__ dst,
                               int* __restrict__ cursor, int* __restrict__ eidx) {
    int e = blockIdx.x * blockDim.x + threadIdx.x;
    if (e >= N_EDGES) return;
    int d = dst[e];
    int pos = atomicAdd(&cursor[d], 1);
    eidx[pos] = src[e];
}

// ---------------------------------------------------------------------------
// Wave-per-node fused aggregation + softmax + finalize.
// R11 change: fully-predicated unroll-by-8 edge loop (was unroll-4 + serial
// remainder). Rationale: R10 profile showed VGPR=16, VALUBusy 29%, HBM 49%,
// occupancy 75% — latency-bound on random 512B row gathers with only 4
// loads in flight per wave. 8 slots/iter doubles MLP; tail slots clamp the
// eidx index to the last valid edge (address valid, row L1-hot) and force
// w=0, eliminating the serial remainder entirely. Feature-row loads are
// issued BEFORE the exp() work so gathers overlap VALU.
// Target VGPR ~48 (stays under the 64-reg occupancy step).
// ---------------------------------------------------------------------------
template<int D, bool RELU>
__global__ __launch_bounds__(256)
void aggregate_wave_kernel(const int* __restrict__ rs, const int* __restrict__ eidx,
                           const float* __restrict__ h,
                           const float* __restrict__ ssrc, const float* __restrict__ sdst,
                           const float* __restrict__ bias, float* __restrict__ out) {
    constexpr int F = HEADS * D;       // 128 or 64
    constexpr int EPL = F / 64;        // elements per lane: 2 or 1
    int lane = threadIdx.x & 63;
    int node = blockIdx.x * (256 / 64) + (threadIdx.x >> 6);
    node = __builtin_amdgcn_readfirstlane(node);
    if (node >= N_NODES) return;
    int hd = lane >> 3;                // head owning this lane's slice

    float sdv = sdst[node * HEADS + hd];
    // self-loop contribution
    float sc0 = ssrc[node * HEADS + hd] + sdv;
    float w0 = __expf(sc0 > 0.f ? sc0 : NEG_SLOPE * sc0);
    float wsum = w0;

    float accx, accy = 0.f;
    if constexpr (EPL == 2) {
        float2 v = *(const float2*)(h + (long)node * F + lane * 2);
        accx = w0 * v.x; accy = w0 * v.y;
    } else {
        accx = w0 * h[(long)node * F + lane];
    }

    int e0 = rs[node], e1 = rs[node + 1];

    // ---- predicated unroll-by-8: 8 independent gather chains in flight ----
    for (int e = e0; e < e1; e += 8) {
        int sE[8];
#pragma unroll
        for (int i = 0; i < 8; ++i) {
            int idx = e + i;
            int ci = idx < e1 ? idx : e1 - 1;   // clamp: address stays valid
            sE[i] = eidx[ci];
        }
        if constexpr (EPL == 2) {
            // issue the 8 big row gathers first, overlap with exp() below
            float2 vE[8];
#pragma unroll
            for (int i = 0; i < 8; ++i)
                vE[i] = *(const float2*)(h + (long)sE[i] * F + lane * 2);
            float wE[8];
#pragma unroll
            for (int i = 0; i < 8; ++i) {
                float sc = ssrc[sE[i] * HEADS + hd] + sdv;
                float w = __expf(sc > 0.f ? sc : NEG_SLOPE * sc);
                wE[i] = (e + i < e1) ? w : 0.f;   // kill tail slots
                wsum += wE[i];
            }
#pragma unroll
            for (int i = 0; i < 8; ++i) {
                accx = fmaf(wE[i], vE[i].x, accx);
                accy = fmaf(wE[i], vE[i].y, accy);
            }
        } else {
            float vE[8];
#pragma unroll
            for (int i = 0; i < 8; ++i)
                vE[i] = h[(long)sE[i] * F + lane];
            float wE[8];
#pragma unroll
            for (int i = 0; i < 8; ++i) {
                float sc = ssrc[sE[i] * HEADS + hd] + sdv;
                float w = __expf(sc > 0.f ? sc : NEG_SLOPE * sc);
                wE[i] = (e + i < e1) ? w : 0.f;
                wsum += wE[i];
            }
#pragma unroll
            for (int i = 0; i < 8; ++i)
                accx = fmaf(wE[i], vE[i], accx);
        }
    }

    float inv = 1.f / (wsum + 1e-16f);
    if constexpr (EPL == 2) {
        float2 b = *(const float2*)(bias + lane * 2);
        float ox = accx * inv + b.x;
        float oy = accy * inv + b.y;
        if (RELU) { ox = fmaxf(ox, 0.f); oy = fmaxf(oy, 0.f); }
        *(float2*)(out + (long)node * F + lane * 2) = make_float2(ox, oy);
    } else {
        float o = accx * inv + bias[lane];
        if (RELU) o = fmaxf(o, 0.f);
        out[(long)node * F + lane] = o;
    }
}

extern "C" void kernel_launch(void* const* d_in, const int* in_sizes, int n_in,
                              void* d_out, int out_size, void* d_ws, size_t ws_size,
                              hipStream_t stream) {
    const float* x   = (const float*)d_in[0];
    const int*   ei  = (const int*)d_in[1];      // [2, N_EDGES] row-major
    const float* W1  = (const float*)d_in[2];
    const float* a1s = (const float*)d_in[3];
    const float* a1d = (const float*)d_in[4];
    const float* b1  = (const float*)d_in[5];
    const float* W2  = (const float*)d_in[6];
    const float* a2s = (const float*)d_in[7];
    const float* a2d = (const float*)d_in[8];
    const float* b2  = (const float*)d_in[9];
    float* out = (float*)d_out;

    const int* src = ei;
    const int* dst = ei + N_EDGES;

    // ---- workspace layout ----
    float* ws = (float*)d_ws;
    float* bufA = ws;                                  // N*128 : h1, later h2 (N*64)
    float* bufB = bufA + (size_t)N_NODES * 128;        // N*128 : out1
    float* ssrc = bufB + (size_t)N_NODES * 128;        // N*8
    float* sdst = ssrc + (size_t)N_NODES * HEADS;      // N*8
    int* counts    = (int*)(sdst + (size_t)N_NODES * HEADS);  // N
    int* row_start = counts + N_NODES;                 // N+1
    int* cursor    = row_start + N_NODES + 1;          // N
    int* bsums     = cursor + N_NODES;                 // 128
    int* eidx      = bsums + 128;                      // N_EDGES

    const int nb_scan = (N_NODES + 1023) / 1024;       // 98

    // ---- CSR build (shared by both layers) ----
    hipMemsetAsync(counts, 0, (size_t)N_NODES * sizeof(int), stream);
    count_kernel<<<(N_EDGES + 255) / 256, 256, 0, stream>>>(dst, counts);
    scan_block_kernel<<<nb_scan, 256, 0, stream>>>(counts, row_start, bsums, N_NODES);
    scan_sums_kernel<<<1, 64, 0, stream>>>(bsums, nb_scan);
    add_offsets_kernel<<<nb_scan, 256, 0, stream>>>(row_start, bsums, cursor, N_NODES);
    scatter_kernel<<<(N_EDGES + 255) / 256, 256, 0, stream>>>(src, dst, cursor, eidx);

    // ---- Layer 1 ----
    gemm_tile_kernel<128, 128, 4><<<(N_NODES + 63) / 64, 256, 0, stream>>>(x, W1, bufA, N_NODES);
    scores_kernel<D1><<<(N_NODES * HEADS + 255) / 256, 256, 0, stream>>>(bufA, a1s, a1d, ssrc, sdst);
    aggregate_wave_kernel<D1, true><<<(N_NODES + 3) / 4, 256, 0, stream>>>(
        row_start, eidx, bufA, ssrc, sdst, b1, bufB);

    // ---- Layer 2 ----
    gemm_tile_kernel<128, 64, 2><<<(N_NODES + 63) / 64, 256, 0, stream>>>(bufB, W2, bufA, N_NODES);
    scores_kernel<D2><<<(N_NODES * HEADS + 255) / 256, 256, 0, stream>>>(bufA, a2s, a2d, ssrc, sdst);
    aggregate_wave_kernel<D2, false><<<(N_NODES + 3) / 4, 256, 0, stream>>>(
        row_start, eidx, bufA, ssrc, sdst, b2, out);
}

// Round 2
// 613.637 us; speedup vs baseline: 1.1447x; 1.1399x over previous
//
#include <hip/hip_runtime.h>
#include <hip/hip_fp16.h>
#include <math.h>

#define N_NODES 100000
#define N_EDGES 1600000
#define IN_DIM 128
#define HEADS 8
#define D1 16
#define D2 8
#define NEG_SLOPE 0.2f

// 16-byte pack of 8 halves (one GEMM output octet / one h-row chunk).
struct __align__(16) half8 { __half2 a, b, c, d; };

// ---------------------------------------------------------------------------
// Register-tiled GEMM (R5 structure, RPT x 8 tile), fp32 compute.
// R12 change: C is stored as fp16 (round-nearest). h is pure interior state
// (feeds scores + the edge gather); storing it half-width halves the
// aggregate's gather bytes — the measured 3.9 TB/s throughput wall.
// All FMA accumulation stays fp32; only the h store/load quantizes.
// ---------------------------------------------------------------------------
template<int K, int OUTC, int RPT>
__global__ __launch_bounds__(256)
void gemm_tile_kernel(const float* __restrict__ A, const float* __restrict__ W,
                      __half* __restrict__ C, int n_rows) {
    constexpr int CT = OUTC / 8;       // col-threads per row group
    constexpr int RT = 256 / CT;       // row-threads
    constexpr int BM = RT * RPT;       // rows per block
    int tid = threadIdx.x;
    int ct = tid % CT;
    int rt = tid / CT;
    int row0 = blockIdx.x * BM + rt * RPT;
    int col0 = ct * 8;

    const float* ap[RPT];
#pragma unroll
    for (int r = 0; r < RPT; ++r) {
        int rr = row0 + r;
        rr = rr < n_rows ? rr : n_rows - 1;   // clamp: keep address valid
        ap[r] = A + (long)rr * K;
    }

    float4 acc[RPT][2];
#pragma unroll
    for (int r = 0; r < RPT; ++r) {
        acc[r][0] = make_float4(0.f, 0.f, 0.f, 0.f);
        acc[r][1] = make_float4(0.f, 0.f, 0.f, 0.f);
    }

    const float* wp = W + col0;
#pragma unroll 2
    for (int c4 = 0; c4 < K / 4; ++c4) {
        float4 a[RPT];
#pragma unroll
        for (int r = 0; r < RPT; ++r) a[r] = *(const float4*)(ap[r] + c4 * 4);
        float4 w0[4], w1[4];
#pragma unroll
        for (int k = 0; k < 4; ++k) {
            const float* wk = wp + (c4 * 4 + k) * OUTC;
            w0[k] = *(const float4*)(wk);
            w1[k] = *(const float4*)(wk + 4);
        }
#pragma unroll
        for (int r = 0; r < RPT; ++r) {
            float a0 = a[r].x, a1 = a[r].y, a2 = a[r].z, a3 = a[r].w;
            acc[r][0].x = fmaf(a0, w0[0].x, acc[r][0].x);
            acc[r][0].y = fmaf(a0, w0[0].y, acc[r][0].y);
            acc[r][0].z = fmaf(a0, w0[0].z, acc[r][0].z);
            acc[r][0].w = fmaf(a0, w0[0].w, acc[r][0].w);
            acc[r][1].x = fmaf(a0, w1[0].x, acc[r][1].x);
            acc[r][1].y = fmaf(a0, w1[0].y, acc[r][1].y);
            acc[r][1].z = fmaf(a0, w1[0].z, acc[r][1].z);
            acc[r][1].w = fmaf(a0, w1[0].w, acc[r][1].w);
            acc[r][0].x = fmaf(a1, w0[1].x, acc[r][0].x);
            acc[r][0].y = fmaf(a1, w0[1].y, acc[r][0].y);
            acc[r][0].z = fmaf(a1, w0[1].z, acc[r][0].z);
            acc[r][0].w = fmaf(a1, w0[1].w, acc[r][0].w);
            acc[r][1].x = fmaf(a1, w1[1].x, acc[r][1].x);
            acc[r][1].y = fmaf(a1, w1[1].y, acc[r][1].y);
            acc[r][1].z = fmaf(a1, w1[1].z, acc[r][1].z);
            acc[r][1].w = fmaf(a1, w1[1].w, acc[r][1].w);
            acc[r][0].x = fmaf(a2, w0[2].x, acc[r][0].x);
            acc[r][0].y = fmaf(a2, w0[2].y, acc[r][0].y);
            acc[r][0].z = fmaf(a2, w0[2].z, acc[r][0].z);
            acc[r][0].w = fmaf(a2, w0[2].w, acc[r][0].w);
            acc[r][1].x = fmaf(a2, w1[2].x, acc[r][1].x);
            acc[r][1].y = fmaf(a2, w1[2].y, acc[r][1].y);
            acc[r][1].z = fmaf(a2, w1[2].z, acc[r][1].z);
            acc[r][1].w = fmaf(a2, w1[2].w, acc[r][1].w);
            acc[r][0].x = fmaf(a3, w0[3].x, acc[r][0].x);
            acc[r][0].y = fmaf(a3, w0[3].y, acc[r][0].y);
            acc[r][0].z = fmaf(a3, w0[3].z, acc[r][0].z);
            acc[r][0].w = fmaf(a3, w0[3].w, acc[r][0].w);
            acc[r][1].x = fmaf(a3, w1[3].x, acc[r][1].x);
            acc[r][1].y = fmaf(a3, w1[3].y, acc[r][1].y);
            acc[r][1].z = fmaf(a3, w1[3].z, acc[r][1].z);
            acc[r][1].w = fmaf(a3, w1[3].w, acc[r][1].w);
        }
    }

#pragma unroll
    for (int r = 0; r < RPT; ++r) {
        int rr = row0 + r;
        if (rr < n_rows) {
            half8 hv;
            hv.a = __floats2half2_rn(acc[r][0].x, acc[r][0].y);
            hv.b = __floats2half2_rn(acc[r][0].z, acc[r][0].w);
            hv.c = __floats2half2_rn(acc[r][1].x, acc[r][1].y);
            hv.d = __floats2half2_rn(acc[r][1].z, acc[r][1].w);
            *(half8*)(C + (long)rr * OUTC + col0) = hv;   // one 16B store
        }
    }
}

// ---------------------------------------------------------------------------
// Attention scores: one thread per (node, head); 16B half8 loads of the D-vec.
// fp32 dot with a_src/a_dst.
// ---------------------------------------------------------------------------
template<int D>
__global__ void scores_kernel(const __half* __restrict__ h,
                              const float* __restrict__ a_src,
                              const float* __restrict__ a_dst,
                              float* __restrict__ s_src,
                              float* __restrict__ s_dst) {
    int i = blockIdx.x * blockDim.x + threadIdx.x;   // over N_NODES*HEADS
    if (i >= N_NODES * HEADS) return;
    int hd = i & 7;
    const half8* hp = (const half8*)(h + (long)i * D);
    const float* as = a_src + hd * D;
    const float* ad = a_dst + hd * D;
    float ss = 0.f, sd = 0.f;
#pragma unroll
    for (int r = 0; r < D / 8; ++r) {
        half8 v8 = hp[r];
        float2 f0 = __half22float2(v8.a);
        float2 f1 = __half22float2(v8.b);
        float2 f2 = __half22float2(v8.c);
        float2 f3 = __half22float2(v8.d);
        float4 s0 = *(const float4*)(as + r * 8);
        float4 s1 = *(const float4*)(as + r * 8 + 4);
        float4 d0 = *(const float4*)(ad + r * 8);
        float4 d1 = *(const float4*)(ad + r * 8 + 4);
        ss = fmaf(f0.x, s0.x, ss); sd = fmaf(f0.x, d0.x, sd);
        ss = fmaf(f0.y, s0.y, ss); sd = fmaf(f0.y, d0.y, sd);
        ss = fmaf(f1.x, s0.z, ss); sd = fmaf(f1.x, d0.z, sd);
        ss = fmaf(f1.y, s0.w, ss); sd = fmaf(f1.y, d0.w, sd);
        ss = fmaf(f2.x, s1.x, ss); sd = fmaf(f2.x, d1.x, sd);
        ss = fmaf(f2.y, s1.y, ss); sd = fmaf(f2.y, d1.y, sd);
        ss = fmaf(f3.x, s1.z, ss); sd = fmaf(f3.x, d1.z, sd);
        ss = fmaf(f3.y, s1.w, ss); sd = fmaf(f3.y, d1.w, sd);
    }
    s_src[i] = ss;
    s_dst[i] = sd;
}

// ---------------------------------------------------------------------------
// CSR build: count -> block scan -> scan of block sums -> add offsets -> scatter
// ---------------------------------------------------------------------------
__global__ void count_kernel(const int* __restrict__ dst, int* __restrict__ counts) {
    int e = blockIdx.x * blockDim.x + threadIdx.x;
    if (e < N_EDGES) atomicAdd(&counts[dst[e]], 1);
}

__global__ void scan_block_kernel(const int* __restrict__ counts, int* __restrict__ rs,
                                  int* __restrict__ bsums, int n) {
    __shared__ int sh[256];
    int tid = threadIdx.x;
    int base = blockIdx.x * 1024 + tid * 4;
    int c0 = (base + 0 < n) ? counts[base + 0] : 0;
    int c1 = (base + 1 < n) ? counts[base + 1] : 0;
    int c2 = (base + 2 < n) ? counts[base + 2] : 0;
    int c3 = (base + 3 < n) ? counts[base + 3] : 0;
    int p1 = c0, p2 = c0 + c1, p3 = c0 + c1 + c2, tot = c0 + c1 + c2 + c3;
    sh[tid] = tot;
    __syncthreads();
    int run = tot;
    for (int off = 1; off < 256; off <<= 1) {
        int add = (tid >= off) ? sh[tid - off] : 0;
        __syncthreads();
        run += add;
        sh[tid] = run;
        __syncthreads();
    }
    int excl = run - tot;
    if (base + 0 < n) rs[base + 0] = excl;
    if (base + 1 < n) rs[base + 1] = excl + p1;
    if (base + 2 < n) rs[base + 2] = excl + p2;
    if (base + 3 < n) rs[base + 3] = excl + p3;
    if (tid == 255) bsums[blockIdx.x] = run;   // block total
}

__global__ void scan_sums_kernel(int* __restrict__ bsums, int nb) {
    if (blockIdx.x == 0 && threadIdx.x == 0) {
        int run = 0;
        for (int i = 0; i < nb; ++i) { int c = bsums[i]; bsums[i] = run; run += c; }
    }
}

__global__ void add_offsets_kernel(int* __restrict__ rs, const int* __restrict__ bsums,
                                   int* __restrict__ cursor, int n) {
    int tid = threadIdx.x;
    int base = blockIdx.x * 1024 + tid * 4;
    int add = bsums[blockIdx.x];
#pragma unroll
    for (int j = 0; j < 4; ++j) {
        int i = base + j;
        if (i < n) { int v = rs[i] + add; rs[i] = v; cursor[i] = v; }
    }
    if (blockIdx.x == 0 && tid == 0) rs[n] = N_EDGES;
}

__global__ void scatter_kernel(const int* __restrict__ src, const int* __restrict__ dst,
                               int* __restrict__ cursor, int* __restrict__ eidx) {
    int e = blockIdx.x * blockDim.x + threadIdx.x;
    if (e >= N_EDGES) return;
    int d = dst[e];
    int pos = atomicAdd(&cursor[d], 1);
    eidx[pos] = src[e];
}

// ---------------------------------------------------------------------------
// Wave-per-node fused aggregation + softmax + finalize.
// R11 post-mortem: unroll-8 (2x MLP) was a NULL — dur 140.6 vs 142.1, FETCH
// identical. The gather path is a ~3.9 TB/s throughput wall, not latency.
// R12 change: gather payload is fp16 (h stored half by the GEMM), halving
// logical bytes/edge 512B->256B (L1) and 256B->128B (L2). Accumulation,
// softmax weights, and outputs stay fp32.
// ---------------------------------------------------------------------------
template<int D, bool RELU>
__global__ __launch_bounds__(256)
void aggregate_wave_kernel(const int* __restrict__ rs, const int* __restrict__ eidx,
                           const __half* __restrict__ h,
                           const float* __restrict__ ssrc, const float* __restrict__ sdst,
                           const float* __restrict__ bias, float* __restrict__ out) {
    constexpr int F = HEADS * D;       // 128 or 64
    constexpr int EPL = F / 64;        // elements per lane: 2 or 1
    int lane = threadIdx.x & 63;
    int node = blockIdx.x * (256 / 64) + (threadIdx.x >> 6);
    node = __builtin_amdgcn_readfirstlane(node);
    if (node >= N_NODES) return;
    int hd = lane >> 3;                // head owning this lane's slice

    float sdv = sdst[node * HEADS + hd];
    // self-loop contribution
    float sc0 = ssrc[node * HEADS + hd] + sdv;
    float w0 = __expf(sc0 > 0.f ? sc0 : NEG_SLOPE * sc0);
    float wsum = w0;

    float accx, accy = 0.f;
    if constexpr (EPL == 2) {
        float2 v = __half22float2(*(const __half2*)(h + (long)node * F + lane * 2));
        accx = w0 * v.x; accy = w0 * v.y;
    } else {
        accx = w0 * __half2float(h[(long)node * F + lane]);
    }

    int e0 = rs[node], e1 = rs[node + 1];

    // ---- predicated unroll-by-8: 8 independent gather chains in flight ----
    for (int e = e0; e < e1; e += 8) {
        int sE[8];
#pragma unroll
        for (int i = 0; i < 8; ++i) {
            int idx = e + i;
            int ci = idx < e1 ? idx : e1 - 1;   // clamp: address stays valid
            sE[i] = eidx[ci];
        }
        if constexpr (EPL == 2) {
            // issue the 8 row gathers first, overlap with exp() below
            __half2 vE[8];
#pragma unroll
            for (int i = 0; i < 8; ++i)
                vE[i] = *(const __half2*)(h + (long)sE[i] * F + lane * 2);
            float wE[8];
#pragma unroll
            for (int i = 0; i < 8; ++i) {
                float sc = ssrc[sE[i] * HEADS + hd] + sdv;
                float w = __expf(sc > 0.f ? sc : NEG_SLOPE * sc);
                wE[i] = (e + i < e1) ? w : 0.f;   // kill tail slots
                wsum += wE[i];
            }
#pragma unroll
            for (int i = 0; i < 8; ++i) {
                float2 v = __half22float2(vE[i]);
                accx = fmaf(wE[i], v.x, accx);
                accy = fmaf(wE[i], v.y, accy);
            }
        } else {
            __half vE[8];
#pragma unroll
            for (int i = 0; i < 8; ++i)
                vE[i] = h[(long)sE[i] * F + lane];
            float wE[8];
#pragma unroll
            for (int i = 0; i < 8; ++i) {
                float sc = ssrc[sE[i] * HEADS + hd] + sdv;
                float w = __expf(sc > 0.f ? sc : NEG_SLOPE * sc);
                wE[i] = (e + i < e1) ? w : 0.f;
                wsum += wE[i];
            }
#pragma unroll
            for (int i = 0; i < 8; ++i)
                accx = fmaf(wE[i], __half2float(vE[i]), accx);
        }
    }

    float inv = 1.f / (wsum + 1e-16f);
    if constexpr (EPL == 2) {
        float2 b = *(const float2*)(bias + lane * 2);
        float ox = accx * inv + b.x;
        float oy = accy * inv + b.y;
        if (RELU) { ox = fmaxf(ox, 0.f); oy = fmaxf(oy, 0.f); }
        *(float2*)(out + (long)node * F + lane * 2) = make_float2(ox, oy);
    } else {
        float o = accx * inv + bias[lane];
        if (RELU) o = fmaxf(o, 0.f);
        out[(long)node * F + lane] = o;
    }
}

extern "C" void kernel_launch(void* const* d_in, const int* in_sizes, int n_in,
                              void* d_out, int out_size, void* d_ws, size_t ws_size,
                              hipStream_t stream) {
    const float* x   = (const float*)d_in[0];
    const int*   ei  = (const int*)d_in[1];      // [2, N_EDGES] row-major
    const float* W1  = (const float*)d_in[2];
    const float* a1s = (const float*)d_in[3];
    const float* a1d = (const float*)d_in[4];
    const float* b1  = (const float*)d_in[5];
    const float* W2  = (const float*)d_in[6];
    const float* a2s = (const float*)d_in[7];
    const float* a2d = (const float*)d_in[8];
    const float* b2  = (const float*)d_in[9];
    float* out = (float*)d_out;

    const int* src = ei;
    const int* dst = ei + N_EDGES;

    // ---- workspace layout (offsets unchanged from R10; h uses bufA as fp16) ----
    float* ws = (float*)d_ws;
    float* bufA = ws;                                  // N*128 : h1/h2 (fp16 now)
    float* bufB = bufA + (size_t)N_NODES * 128;        // N*128 : out1 (fp32)
    float* ssrc = bufB + (size_t)N_NODES * 128;        // N*8
    float* sdst = ssrc + (size_t)N_NODES * HEADS;      // N*8
    int* counts    = (int*)(sdst + (size_t)N_NODES * HEADS);  // N
    int* row_start = counts + N_NODES;                 // N+1
    int* cursor    = row_start + N_NODES + 1;          // N
    int* bsums     = cursor + N_NODES;                 // 128
    int* eidx      = bsums + 128;                      // N_EDGES

    __half* hbuf = (__half*)bufA;

    const int nb_scan = (N_NODES + 1023) / 1024;       // 98

    // ---- CSR build (shared by both layers) ----
    hipMemsetAsync(counts, 0, (size_t)N_NODES * sizeof(int), stream);
    count_kernel<<<(N_EDGES + 255) / 256, 256, 0, stream>>>(dst, counts);
    scan_block_kernel<<<nb_scan, 256, 0, stream>>>(counts, row_start, bsums, N_NODES);
    scan_sums_kernel<<<1, 64, 0, stream>>>(bsums, nb_scan);
    add_offsets_kernel<<<nb_scan, 256, 0, stream>>>(row_start, bsums, cursor, N_NODES);
    scatter_kernel<<<(N_EDGES + 255) / 256, 256, 0, stream>>>(src, dst, cursor, eidx);

    // ---- Layer 1 ----
    gemm_tile_kernel<128, 128, 4><<<(N_NODES + 63) / 64, 256, 0, stream>>>(x, W1, hbuf, N_NODES);
    scores_kernel<D1><<<(N_NODES * HEADS + 255) / 256, 256, 0, stream>>>(hbuf, a1s, a1d, ssrc, sdst);
    aggregate_wave_kernel<D1, true><<<(N_NODES + 3) / 4, 256, 0, stream>>>(
        row_start, eidx, hbuf, ssrc, sdst, b1, bufB);

    // ---- Layer 2 ----
    gemm_tile_kernel<128, 64, 2><<<(N_NODES + 63) / 64, 256, 0, stream>>>(bufB, W2, hbuf, N_NODES);
    scores_kernel<D2><<<(N_NODES * HEADS + 255) / 256, 256, 0, stream>>>(hbuf, a2s, a2d, ssrc, sdst);
    aggregate_wave_kernel<D2, false><<<(N_NODES + 3) / 4, 256, 0, stream>>>(
        row_start, eidx, hbuf, ssrc, sdst, b2, out);
}

// Round 3
// 475.200 us; speedup vs baseline: 1.4782x; 1.2913x over previous
//
#include <hip/hip_runtime.h>
#include <hip/hip_fp16.h>
#include <math.h>

#define N_NODES 100000
#define N_EDGES 1600000
#define IN_DIM 128
#define HEADS 8
#define D1 16
#define D2 8
#define NEG_SLOPE 0.2f

#define NBKT ((N_NODES + 255) / 256)   // 391 buckets of 256 dst nodes
#define PART_CHUNK 4096

// 16-byte pack of 8 halves (one GEMM output octet / one h-row chunk).
struct __align__(16) half8 { __half2 a, b, c, d; };

// ---------------------------------------------------------------------------
// Register-tiled GEMM (R5 structure, RPT x 8 tile), fp32 compute, fp16 store.
// ---------------------------------------------------------------------------
template<int K, int OUTC, int RPT>
__global__ __launch_bounds__(256)
void gemm_tile_kernel(const float* __restrict__ A, const float* __restrict__ W,
                      __half* __restrict__ C, int n_rows) {
    constexpr int CT = OUTC / 8;       // col-threads per row group
    constexpr int RT = 256 / CT;       // row-threads
    constexpr int BM = RT * RPT;       // rows per block
    int tid = threadIdx.x;
    int ct = tid % CT;
    int rt = tid / CT;
    int row0 = blockIdx.x * BM + rt * RPT;
    int col0 = ct * 8;

    const float* ap[RPT];
#pragma unroll
    for (int r = 0; r < RPT; ++r) {
        int rr = row0 + r;
        rr = rr < n_rows ? rr : n_rows - 1;   // clamp: keep address valid
        ap[r] = A + (long)rr * K;
    }

    float4 acc[RPT][2];
#pragma unroll
    for (int r = 0; r < RPT; ++r) {
        acc[r][0] = make_float4(0.f, 0.f, 0.f, 0.f);
        acc[r][1] = make_float4(0.f, 0.f, 0.f, 0.f);
    }

    const float* wp = W + col0;
#pragma unroll 2
    for (int c4 = 0; c4 < K / 4; ++c4) {
        float4 a[RPT];
#pragma unroll
        for (int r = 0; r < RPT; ++r) a[r] = *(const float4*)(ap[r] + c4 * 4);
        float4 w0[4], w1[4];
#pragma unroll
        for (int k = 0; k < 4; ++k) {
            const float* wk = wp + (c4 * 4 + k) * OUTC;
            w0[k] = *(const float4*)(wk);
            w1[k] = *(const float4*)(wk + 4);
        }
#pragma unroll
        for (int r = 0; r < RPT; ++r) {
            float a0 = a[r].x, a1 = a[r].y, a2 = a[r].z, a3 = a[r].w;
            acc[r][0].x = fmaf(a0, w0[0].x, acc[r][0].x);
            acc[r][0].y = fmaf(a0, w0[0].y, acc[r][0].y);
            acc[r][0].z = fmaf(a0, w0[0].z, acc[r][0].z);
            acc[r][0].w = fmaf(a0, w0[0].w, acc[r][0].w);
            acc[r][1].x = fmaf(a0, w1[0].x, acc[r][1].x);
            acc[r][1].y = fmaf(a0, w1[0].y, acc[r][1].y);
            acc[r][1].z = fmaf(a0, w1[0].z, acc[r][1].z);
            acc[r][1].w = fmaf(a0, w1[0].w, acc[r][1].w);
            acc[r][0].x = fmaf(a1, w0[1].x, acc[r][0].x);
            acc[r][0].y = fmaf(a1, w0[1].y, acc[r][0].y);
            acc[r][0].z = fmaf(a1, w0[1].z, acc[r][0].z);
            acc[r][0].w = fmaf(a1, w0[1].w, acc[r][0].w);
            acc[r][1].x = fmaf(a1, w1[1].x, acc[r][1].x);
            acc[r][1].y = fmaf(a1, w1[1].y, acc[r][1].y);
            acc[r][1].z = fmaf(a1, w1[1].z, acc[r][1].z);
            acc[r][1].w = fmaf(a1, w1[1].w, acc[r][1].w);
            acc[r][0].x = fmaf(a2, w0[2].x, acc[r][0].x);
            acc[r][0].y = fmaf(a2, w0[2].y, acc[r][0].y);
            acc[r][0].z = fmaf(a2, w0[2].z, acc[r][0].z);
            acc[r][0].w = fmaf(a2, w0[2].w, acc[r][0].w);
            acc[r][1].x = fmaf(a2, w1[2].x, acc[r][1].x);
            acc[r][1].y = fmaf(a2, w1[2].y, acc[r][1].y);
            acc[r][1].z = fmaf(a2, w1[2].z, acc[r][1].z);
            acc[r][1].w = fmaf(a2, w1[2].w, acc[r][1].w);
            acc[r][0].x = fmaf(a3, w0[3].x, acc[r][0].x);
            acc[r][0].y = fmaf(a3, w0[3].y, acc[r][0].y);
            acc[r][0].z = fmaf(a3, w0[3].z, acc[r][0].z);
            acc[r][0].w = fmaf(a3, w0[3].w, acc[r][0].w);
            acc[r][1].x = fmaf(a3, w1[3].x, acc[r][1].x);
            acc[r][1].y = fmaf(a3, w1[3].y, acc[r][1].y);
            acc[r][1].z = fmaf(a3, w1[3].z, acc[r][1].z);
            acc[r][1].w = fmaf(a3, w1[3].w, acc[r][1].w);
        }
    }

#pragma unroll
    for (int r = 0; r < RPT; ++r) {
        int rr = row0 + r;
        if (rr < n_rows) {
            half8 hv;
            hv.a = __floats2half2_rn(acc[r][0].x, acc[r][0].y);
            hv.b = __floats2half2_rn(acc[r][0].z, acc[r][0].w);
            hv.c = __floats2half2_rn(acc[r][1].x, acc[r][1].y);
            hv.d = __floats2half2_rn(acc[r][1].z, acc[r][1].w);
            *(half8*)(C + (long)rr * OUTC + col0) = hv;   // one 16B store
        }
    }
}

// ---------------------------------------------------------------------------
// Attention scores: one thread per (node, head); 16B half8 loads of the D-vec.
// ---------------------------------------------------------------------------
template<int D>
__global__ void scores_kernel(const __half* __restrict__ h,
                              const float* __restrict__ a_src,
                              const float* __restrict__ a_dst,
                              float* __restrict__ s_src,
                              float* __restrict__ s_dst) {
    int i = blockIdx.x * blockDim.x + threadIdx.x;   // over N_NODES*HEADS
    if (i >= N_NODES * HEADS) return;
    int hd = i & 7;
    const half8* hp = (const half8*)(h + (long)i * D);
    const float* as = a_src + hd * D;
    const float* ad = a_dst + hd * D;
    float ss = 0.f, sd = 0.f;
#pragma unroll
    for (int r = 0; r < D / 8; ++r) {
        half8 v8 = hp[r];
        float2 f0 = __half22float2(v8.a);
        float2 f1 = __half22float2(v8.b);
        float2 f2 = __half22float2(v8.c);
        float2 f3 = __half22float2(v8.d);
        float4 s0 = *(const float4*)(as + r * 8);
        float4 s1 = *(const float4*)(as + r * 8 + 4);
        float4 d0 = *(const float4*)(ad + r * 8);
        float4 d1 = *(const float4*)(ad + r * 8 + 4);
        ss = fmaf(f0.x, s0.x, ss); sd = fmaf(f0.x, d0.x, sd);
        ss = fmaf(f0.y, s0.y, ss); sd = fmaf(f0.y, d0.y, sd);
        ss = fmaf(f1.x, s0.z, ss); sd = fmaf(f1.x, d0.z, sd);
        ss = fmaf(f1.y, s0.w, ss); sd = fmaf(f1.y, d0.w, sd);
        ss = fmaf(f2.x, s1.x, ss); sd = fmaf(f2.x, d1.x, sd);
        ss = fmaf(f2.y, s1.y, ss); sd = fmaf(f2.y, d1.y, sd);
        ss = fmaf(f3.x, s1.z, ss); sd = fmaf(f3.x, d1.z, sd);
        ss = fmaf(f3.y, s1.w, ss); sd = fmaf(f3.y, d1.w, sd);
    }
    s_src[i] = ss;
    s_dst[i] = sd;
}

// ---------------------------------------------------------------------------
// R13 CSR build: bucketed two-phase partition replaces count+scans+scatter.
// Old scatter_kernel: eidx[atomicAdd(cursor[dst])] = src kept 100K open write
// frontiers -> 105 MB HBM writes for 6.4 MB of data (16x amplification),
// 127 us. New scheme: 391 buckets of 256 dst nodes. Phase 1 partitions
// (src,dst) pairs into bucket regions (391 frontiers, concurrent writers to
// a bucket land adjacent -> lines fill while L2-hot). Phase 2: one block per
// bucket builds the exact CSR segment locally in LDS and writes row_start +
// eidx into its private contiguous region.
// ---------------------------------------------------------------------------
__global__ __launch_bounds__(256)
void hist_kernel(const int* __restrict__ dst, int* __restrict__ ghist) {
    __shared__ int hist[NBKT];
    for (int i = threadIdx.x; i < NBKT; i += 256) hist[i] = 0;
    __syncthreads();
    int base = blockIdx.x * (256 * 8);
#pragma unroll
    for (int j = 0; j < 8; ++j) {
        int e = base + j * 256 + threadIdx.x;
        if (e < N_EDGES) atomicAdd(&hist[dst[e] >> 8], 1);
    }
    __syncthreads();
    for (int i = threadIdx.x; i < NBKT; i += 256) {
        int c = hist[i];
        if (c) atomicAdd(&ghist[i], c);
    }
}

__global__ __launch_bounds__(512)
void bscan_kernel(const int* __restrict__ ghist, int* __restrict__ bstart,
                  int* __restrict__ bcursor) {
    __shared__ int sh[512];
    int tid = threadIdx.x;
    int v = (tid < NBKT) ? ghist[tid] : 0;
    sh[tid] = v;
    __syncthreads();
    int run = v;
    for (int off = 1; off < 512; off <<= 1) {
        int add = (tid >= off) ? sh[tid - off] : 0;
        __syncthreads();
        run += add;
        sh[tid] = run;
        __syncthreads();
    }
    int excl = run - v;
    if (tid < NBKT) { bstart[tid] = excl; bcursor[tid] = excl; }
    if (tid == NBKT - 1) bstart[NBKT] = excl + v;   // == N_EDGES
}

__global__ __launch_bounds__(256)
void partition_kernel(const int* __restrict__ src, const int* __restrict__ dst,
                      int* __restrict__ bcursor, int2* __restrict__ bpairs) {
    __shared__ int hist[NBKT];
    for (int i = threadIdx.x; i < NBKT; i += 256) hist[i] = 0;
    __syncthreads();
    int e0 = blockIdx.x * PART_CHUNK;
    int e1 = e0 + PART_CHUNK < N_EDGES ? e0 + PART_CHUNK : N_EDGES;
    for (int e = e0 + threadIdx.x; e < e1; e += 256)
        atomicAdd(&hist[dst[e] >> 8], 1);
    __syncthreads();
    // reserve a contiguous range per (block, bucket): one global atomic each
    for (int i = threadIdx.x; i < NBKT; i += 256) {
        int c = hist[i];
        if (c) hist[i] = atomicAdd(&bcursor[i], c);
    }
    __syncthreads();
    for (int e = e0 + threadIdx.x; e < e1; e += 256) {
        int d = dst[e];
        int pos = atomicAdd(&hist[d >> 8], 1);
        bpairs[pos] = make_int2(src[e], d);
    }
}

__global__ __launch_bounds__(256)
void localcsr_kernel(const int* __restrict__ bstart, const int2* __restrict__ bpairs,
                     int* __restrict__ row_start, int* __restrict__ eidx) {
    __shared__ int cnt[256];
    __shared__ int sh[256];
    __shared__ int cur[256];
    int b = blockIdx.x;
    int tid = threadIdx.x;
    int n0 = b << 8;
    int m0 = bstart[b], m1 = bstart[b + 1];
    cnt[tid] = 0;
    __syncthreads();
    for (int k = m0 + tid; k < m1; k += 256)
        atomicAdd(&cnt[bpairs[k].y & 255], 1);
    __syncthreads();
    int c = cnt[tid];
    sh[tid] = c;
    __syncthreads();
    int run = c;
    for (int off = 1; off < 256; off <<= 1) {
        int add = (tid >= off) ? sh[tid - off] : 0;
        __syncthreads();
        run += add;
        sh[tid] = run;
        __syncthreads();
    }
    int excl = run - c;
    cur[tid] = m0 + excl;
    if (n0 + tid < N_NODES) row_start[n0 + tid] = m0 + excl;
    __syncthreads();
    for (int k = m0 + tid; k < m1; k += 256) {
        int2 p = bpairs[k];
        int pos = atomicAdd(&cur[p.y & 255], 1);
        eidx[pos] = p.x;
    }
    if (b == 0 && tid == 0) row_start[N_NODES] = N_EDGES;
}

// ---------------------------------------------------------------------------
// Wave-per-node fused aggregation + softmax + finalize (fp16 gather payload).
// ---------------------------------------------------------------------------
template<int D, bool RELU>
__global__ __launch_bounds__(256)
void aggregate_wave_kernel(const int* __restrict__ rs, const int* __restrict__ eidx,
                           const __half* __restrict__ h,
                           const float* __restrict__ ssrc, const float* __restrict__ sdst,
                           const float* __restrict__ bias, float* __restrict__ out) {
    constexpr int F = HEADS * D;       // 128 or 64
    constexpr int EPL = F / 64;        // elements per lane: 2 or 1
    int lane = threadIdx.x & 63;
    int node = blockIdx.x * (256 / 64) + (threadIdx.x >> 6);
    node = __builtin_amdgcn_readfirstlane(node);
    if (node >= N_NODES) return;
    int hd = lane >> 3;                // head owning this lane's slice

    float sdv = sdst[node * HEADS + hd];
    // self-loop contribution
    float sc0 = ssrc[node * HEADS + hd] + sdv;
    float w0 = __expf(sc0 > 0.f ? sc0 : NEG_SLOPE * sc0);
    float wsum = w0;

    float accx, accy = 0.f;
    if constexpr (EPL == 2) {
        float2 v = __half22float2(*(const __half2*)(h + (long)node * F + lane * 2));
        accx = w0 * v.x; accy = w0 * v.y;
    } else {
        accx = w0 * __half2float(h[(long)node * F + lane]);
    }

    int e0 = rs[node], e1 = rs[node + 1];

    // ---- predicated unroll-by-8: 8 independent gather chains in flight ----
    for (int e = e0; e < e1; e += 8) {
        int sE[8];
#pragma unroll
        for (int i = 0; i < 8; ++i) {
            int idx = e + i;
            int ci = idx < e1 ? idx : e1 - 1;   // clamp: address stays valid
            sE[i] = eidx[ci];
        }
        if constexpr (EPL == 2) {
            __half2 vE[8];
#pragma unroll
            for (int i = 0; i < 8; ++i)
                vE[i] = *(const __half2*)(h + (long)sE[i] * F + lane * 2);
            float wE[8];
#pragma unroll
            for (int i = 0; i < 8; ++i) {
                float sc = ssrc[sE[i] * HEADS + hd] + sdv;
                float w = __expf(sc > 0.f ? sc : NEG_SLOPE * sc);
                wE[i] = (e + i < e1) ? w : 0.f;   // kill tail slots
                wsum += wE[i];
            }
#pragma unroll
            for (int i = 0; i < 8; ++i) {
                float2 v = __half22float2(vE[i]);
                accx = fmaf(wE[i], v.x, accx);
                accy = fmaf(wE[i], v.y, accy);
            }
        } else {
            __half vE[8];
#pragma unroll
            for (int i = 0; i < 8; ++i)
                vE[i] = h[(long)sE[i] * F + lane];
            float wE[8];
#pragma unroll
            for (int i = 0; i < 8; ++i) {
                float sc = ssrc[sE[i] * HEADS + hd] + sdv;
                float w = __expf(sc > 0.f ? sc : NEG_SLOPE * sc);
                wE[i] = (e + i < e1) ? w : 0.f;
                wsum += wE[i];
            }
#pragma unroll
            for (int i = 0; i < 8; ++i)
                accx = fmaf(wE[i], __half2float(vE[i]), accx);
        }
    }

    float inv = 1.f / (wsum + 1e-16f);
    if constexpr (EPL == 2) {
        float2 b = *(const float2*)(bias + lane * 2);
        float ox = accx * inv + b.x;
        float oy = accy * inv + b.y;
        if (RELU) { ox = fmaxf(ox, 0.f); oy = fmaxf(oy, 0.f); }
        *(float2*)(out + (long)node * F + lane * 2) = make_float2(ox, oy);
    } else {
        float o = accx * inv + bias[lane];
        if (RELU) o = fmaxf(o, 0.f);
        out[(long)node * F + lane] = o;
    }
}

extern "C" void kernel_launch(void* const* d_in, const int* in_sizes, int n_in,
                              void* d_out, int out_size, void* d_ws, size_t ws_size,
                              hipStream_t stream) {
    const float* x   = (const float*)d_in[0];
    const int*   ei  = (const int*)d_in[1];      // [2, N_EDGES] row-major
    const float* W1  = (const float*)d_in[2];
    const float* a1s = (const float*)d_in[3];
    const float* a1d = (const float*)d_in[4];
    const float* b1  = (const float*)d_in[5];
    const float* W2  = (const float*)d_in[6];
    const float* a2s = (const float*)d_in[7];
    const float* a2d = (const float*)d_in[8];
    const float* b2  = (const float*)d_in[9];
    float* out = (float*)d_out;

    const int* src = ei;
    const int* dst = ei + N_EDGES;

    // ---- workspace layout ----
    float* ws = (float*)d_ws;
    float* bufA = ws;                                  // N*128 f32 slot: h1/h2 (fp16)
    float* bufB = bufA + (size_t)N_NODES * 128;        // N*128 : bpairs scratch, then out1
    float* ssrc = bufB + (size_t)N_NODES * 128;        // N*8
    float* sdst = ssrc + (size_t)N_NODES * HEADS;      // N*8
    int* counts    = (int*)(sdst + (size_t)N_NODES * HEADS);  // N ints (carved below)
    int* row_start = counts + N_NODES;                 // N+1
    int* cursor    = row_start + N_NODES + 1;          // N (unused, layout compat)
    int* bsums     = cursor + N_NODES;                 // 128 (unused)
    int* eidx      = bsums + 128;                      // N_EDGES

    int* ghist   = counts;            // NBKT
    int* bstart  = counts + 512;      // NBKT+1
    int* bcursor = counts + 1024;     // NBKT
    int2* bpairs = (int2*)bufB;       // E*8B; dead before aggregate L1 writes bufB

    __half* hbuf = (__half*)bufA;

    // ---- CSR build (bucketed two-phase; shared by both layers) ----
    hipMemsetAsync(ghist, 0, NBKT * sizeof(int), stream);
    hist_kernel<<<(N_EDGES + 2047) / 2048, 256, 0, stream>>>(dst, ghist);
    bscan_kernel<<<1, 512, 0, stream>>>(ghist, bstart, bcursor);
    partition_kernel<<<(N_EDGES + PART_CHUNK - 1) / PART_CHUNK, 256, 0, stream>>>(
        src, dst, bcursor, bpairs);
    localcsr_kernel<<<NBKT, 256, 0, stream>>>(bstart, bpairs, row_start, eidx);

    // ---- Layer 1 ----
    gemm_tile_kernel<128, 128, 4><<<(N_NODES + 63) / 64, 256, 0, stream>>>(x, W1, hbuf, N_NODES);
    scores_kernel<D1><<<(N_NODES * HEADS + 255) / 256, 256, 0, stream>>>(hbuf, a1s, a1d, ssrc, sdst);
    aggregate_wave_kernel<D1, true><<<(N_NODES + 3) / 4, 256, 0, stream>>>(
        row_start, eidx, hbuf, ssrc, sdst, b1, bufB);

    // ---- Layer 2 ----
    gemm_tile_kernel<128, 64, 2><<<(N_NODES + 63) / 64, 256, 0, stream>>>(bufB, W2, hbuf, N_NODES);
    scores_kernel<D2><<<(N_NODES * HEADS + 255) / 256, 256, 0, stream>>>(hbuf, a2s, a2d, ssrc, sdst);
    aggregate_wave_kernel<D2, false><<<(N_NODES + 3) / 4, 256, 0, stream>>>(
        row_start, eidx, hbuf, ssrc, sdst, b2, out);
}

// Round 4
// 379.686 us; speedup vs baseline: 1.8500x; 1.2516x over previous
//
#include <hip/hip_runtime.h>
#include <hip/hip_fp16.h>
#include <math.h>

#define N_NODES 100000
#define N_EDGES 1600000
#define IN_DIM 128
#define HEADS 8
#define D1 16
#define D2 8
#define NEG_SLOPE 0.2f

#define NBKT ((N_NODES + 255) / 256)   // 391 buckets of 256 dst nodes
#define PART_CHUNK 4096

typedef _Float16 f16x8 __attribute__((ext_vector_type(8)));
typedef float    f32x4 __attribute__((ext_vector_type(4)));

// 16-byte pack of 8 halves.
struct __align__(16) half8 { __half2 a, b, c, d; };

// ---------------------------------------------------------------------------
// R14: MFMA GEMM. R13 profile: fp32 vector GEMM was the top dispatch at
// 110 us with MfmaUtil=0, VALUBusy=22%, HBM 5.8% — the matrix pipe idle.
// This kernel replicates the guide's HW-verified m90/m92 fragment pattern:
//   A-frag: lane reads A[row0+(lane&15)][k0+(lane>>4)*8 .. +8]  (8 contig k)
//   B-frag: lane reads Bt[col0+(lane&15)][k0+(lane>>4)*8 .. +8] (Bt = W^T)
//   C/D  : row=(lane>>4)*4+reg, col=lane&15  (m89/m91, dtype-independent)
// fp16 inputs, fp32 accumulation, fp16 output (h is interior state).
// Block = 256 thr = 4 waves; wave w owns rows [row0+w*16, +16) x all OUTC.
// ---------------------------------------------------------------------------
template<int OUTC>
__global__ __launch_bounds__(256)
void gemm_mfma_kernel(const __half* __restrict__ A, const __half* __restrict__ Bt,
                      __half* __restrict__ C, int n_rows) {
    constexpr int K = 128;
    constexpr int NT = OUTC / 16;      // col tiles: 8 (L1) or 4 (L2)
    int wid  = threadIdx.x >> 6;
    int lane = threadIdx.x & 63;
    int row0 = blockIdx.x * 64 + wid * 16;
    int lr   = lane & 15;              // M-row within tile (A) / N-col (B)
    int ks   = (lane >> 4) * 8;        // k-slice base within 32-k subtile

    int arow = row0 + lr;
    arow = arow < n_rows ? arow : n_rows - 1;   // clamp tail, stores guarded
    const __half* ap = A + (long)arow * K + ks;

    // 4 A-fragments cover K=128 (4 x 32-k MFMA steps)
    f16x8 a0 = *(const f16x8*)(ap);
    f16x8 a1 = *(const f16x8*)(ap + 32);
    f16x8 a2 = *(const f16x8*)(ap + 64);
    f16x8 a3 = *(const f16x8*)(ap + 96);

    f32x4 acc[NT];
#pragma unroll
    for (int j = 0; j < NT; ++j) acc[j] = (f32x4)(0.f);

#pragma unroll
    for (int j = 0; j < NT; ++j) {
        const __half* bp = Bt + (long)(j * 16 + lr) * K + ks;
        f16x8 b0 = *(const f16x8*)(bp);
        f16x8 b1 = *(const f16x8*)(bp + 32);
        f16x8 b2 = *(const f16x8*)(bp + 64);
        f16x8 b3 = *(const f16x8*)(bp + 96);
        acc[j] = __builtin_amdgcn_mfma_f32_16x16x32_f16(a0, b0, acc[j], 0, 0, 0);
        acc[j] = __builtin_amdgcn_mfma_f32_16x16x32_f16(a1, b1, acc[j], 0, 0, 0);
        acc[j] = __builtin_amdgcn_mfma_f32_16x16x32_f16(a2, b2, acc[j], 0, 0, 0);
        acc[j] = __builtin_amdgcn_mfma_f32_16x16x32_f16(a3, b3, acc[j], 0, 0, 0);
    }

    // C/D: row = row0 + (lane>>4)*4 + r, col = j*16 + (lane&15)
    int rbase = row0 + (lane >> 4) * 4;
#pragma unroll
    for (int r = 0; r < 4; ++r) {
        int rr = rbase + r;
        if (rr < n_rows) {
            __half* cp = C + (long)rr * OUTC + lr;
#pragma unroll
            for (int j = 0; j < NT; ++j)
                cp[j * 16] = __float2half(acc[j][r]);
        }
    }
}

// x (fp32) -> xh (fp16), 8 elems/thread.
__global__ __launch_bounds__(256)
void convert_x_kernel(const float* __restrict__ x, __half* __restrict__ xh) {
    int i = blockIdx.x * blockDim.x + threadIdx.x;   // over N*128/8
    if (i >= N_NODES * IN_DIM / 8) return;
    const float4* p = (const float4*)(x + (long)i * 8);
    float4 v0 = p[0], v1 = p[1];
    half8 hv;
    hv.a = __floats2half2_rn(v0.x, v0.y);
    hv.b = __floats2half2_rn(v0.z, v0.w);
    hv.c = __floats2half2_rn(v1.x, v1.y);
    hv.d = __floats2half2_rn(v1.z, v1.w);
    *(half8*)(xh + (long)i * 8) = hv;
}

// W [K][OUTC] fp32 -> Wt [OUTC][K] fp16 (tiny; coalescing irrelevant).
__global__ __launch_bounds__(256)
void convert_wt_kernel(const float* __restrict__ W, __half* __restrict__ Wt,
                       int K, int OUTC) {
    int idx = blockIdx.x * blockDim.x + threadIdx.x;
    if (idx >= K * OUTC) return;
    int k = idx / OUTC, j = idx % OUTC;
    Wt[(long)j * K + k] = __float2half(W[idx]);
}

// ---------------------------------------------------------------------------
// Attention scores: one thread per (node, head); 16B half8 loads of the D-vec.
// ---------------------------------------------------------------------------
template<int D>
__global__ void scores_kernel(const __half* __restrict__ h,
                              const float* __restrict__ a_src,
                              const float* __restrict__ a_dst,
                              float* __restrict__ s_src,
                              float* __restrict__ s_dst) {
    int i = blockIdx.x * blockDim.x + threadIdx.x;   // over N_NODES*HEADS
    if (i >= N_NODES * HEADS) return;
    int hd = i & 7;
    const half8* hp = (const half8*)(h + (long)i * D);
    const float* as = a_src + hd * D;
    const float* ad = a_dst + hd * D;
    float ss = 0.f, sd = 0.f;
#pragma unroll
    for (int r = 0; r < D / 8; ++r) {
        half8 v8 = hp[r];
        float2 f0 = __half22float2(v8.a);
        float2 f1 = __half22float2(v8.b);
        float2 f2 = __half22float2(v8.c);
        float2 f3 = __half22float2(v8.d);
        float4 s0 = *(const float4*)(as + r * 8);
        float4 s1 = *(const float4*)(as + r * 8 + 4);
        float4 d0 = *(const float4*)(ad + r * 8);
        float4 d1 = *(const float4*)(ad + r * 8 + 4);
        ss = fmaf(f0.x, s0.x, ss); sd = fmaf(f0.x, d0.x, sd);
        ss = fmaf(f0.y, s0.y, ss); sd = fmaf(f0.y, d0.y, sd);
        ss = fmaf(f1.x, s0.z, ss); sd = fmaf(f1.x, d0.z, sd);
        ss = fmaf(f1.y, s0.w, ss); sd = fmaf(f1.y, d0.w, sd);
        ss = fmaf(f2.x, s1.x, ss); sd = fmaf(f2.x, d1.x, sd);
        ss = fmaf(f2.y, s1.y, ss); sd = fmaf(f2.y, d1.y, sd);
        ss = fmaf(f3.x, s1.z, ss); sd = fmaf(f3.x, d1.z, sd);
        ss = fmaf(f3.y, s1.w, ss); sd = fmaf(f3.y, d1.w, sd);
    }
    s_src[i] = ss;
    s_dst[i] = sd;
}

// ---------------------------------------------------------------------------
// Bucketed two-phase CSR build (R13; scatter write-amplification fix).
// ---------------------------------------------------------------------------
__global__ __launch_bounds__(256)
void hist_kernel(const int* __restrict__ dst, int* __restrict__ ghist) {
    __shared__ int hist[NBKT];
    for (int i = threadIdx.x; i < NBKT; i += 256) hist[i] = 0;
    __syncthreads();
    int base = blockIdx.x * (256 * 8);
#pragma unroll
    for (int j = 0; j < 8; ++j) {
        int e = base + j * 256 + threadIdx.x;
        if (e < N_EDGES) atomicAdd(&hist[dst[e] >> 8], 1);
    }
    __syncthreads();
    for (int i = threadIdx.x; i < NBKT; i += 256) {
        int c = hist[i];
        if (c) atomicAdd(&ghist[i], c);
    }
}

__global__ __launch_bounds__(512)
void bscan_kernel(const int* __restrict__ ghist, int* __restrict__ bstart,
                  int* __restrict__ bcursor) {
    __shared__ int sh[512];
    int tid = threadIdx.x;
    int v = (tid < NBKT) ? ghist[tid] : 0;
    sh[tid] = v;
    __syncthreads();
    int run = v;
    for (int off = 1; off < 512; off <<= 1) {
        int add = (tid >= off) ? sh[tid - off] : 0;
        __syncthreads();
        run += add;
        sh[tid] = run;
        __syncthreads();
    }
    int excl = run - v;
    if (tid < NBKT) { bstart[tid] = excl; bcursor[tid] = excl; }
    if (tid == NBKT - 1) bstart[NBKT] = excl + v;   // == N_EDGES
}

__global__ __launch_bounds__(256)
void partition_kernel(const int* __restrict__ src, const int* __restrict__ dst,
                      int* __restrict__ bcursor, int2* __restrict__ bpairs) {
    __shared__ int hist[NBKT];
    for (int i = threadIdx.x; i < NBKT; i += 256) hist[i] = 0;
    __syncthreads();
    int e0 = blockIdx.x * PART_CHUNK;
    int e1 = e0 + PART_CHUNK < N_EDGES ? e0 + PART_CHUNK : N_EDGES;
    for (int e = e0 + threadIdx.x; e < e1; e += 256)
        atomicAdd(&hist[dst[e] >> 8], 1);
    __syncthreads();
    for (int i = threadIdx.x; i < NBKT; i += 256) {
        int c = hist[i];
        if (c) hist[i] = atomicAdd(&bcursor[i], c);
    }
    __syncthreads();
    for (int e = e0 + threadIdx.x; e < e1; e += 256) {
        int d = dst[e];
        int pos = atomicAdd(&hist[d >> 8], 1);
        bpairs[pos] = make_int2(src[e], d);
    }
}

__global__ __launch_bounds__(256)
void localcsr_kernel(const int* __restrict__ bstart, const int2* __restrict__ bpairs,
                     int* __restrict__ row_start, int* __restrict__ eidx) {
    __shared__ int cnt[256];
    __shared__ int sh[256];
    __shared__ int cur[256];
    int b = blockIdx.x;
    int tid = threadIdx.x;
    int n0 = b << 8;
    int m0 = bstart[b], m1 = bstart[b + 1];
    cnt[tid] = 0;
    __syncthreads();
    for (int k = m0 + tid; k < m1; k += 256)
        atomicAdd(&cnt[bpairs[k].y & 255], 1);
    __syncthreads();
    int c = cnt[tid];
    sh[tid] = c;
    __syncthreads();
    int run = c;
    for (int off = 1; off < 256; off <<= 1) {
        int add = (tid >= off) ? sh[tid - off] : 0;
        __syncthreads();
        run += add;
        sh[tid] = run;
        __syncthreads();
    }
    int excl = run - c;
    cur[tid] = m0 + excl;
    if (n0 + tid < N_NODES) row_start[n0 + tid] = m0 + excl;
    __syncthreads();
    for (int k = m0 + tid; k < m1; k += 256) {
        int2 p = bpairs[k];
        int pos = atomicAdd(&cur[p.y & 255], 1);
        eidx[pos] = p.x;
    }
    if (b == 0 && tid == 0) row_start[N_NODES] = N_EDGES;
}

// ---------------------------------------------------------------------------
// Wave-per-node fused aggregation + softmax + finalize (fp16 gather payload).
// R14: templated output type — layer 1 emits fp16 so the MFMA GEMM2 consumes
// it natively (also halves agg-L1 write traffic). Final layer stays fp32.
// ---------------------------------------------------------------------------
template<int D, bool RELU, typename OT>
__global__ __launch_bounds__(256)
void aggregate_wave_kernel(const int* __restrict__ rs, const int* __restrict__ eidx,
                           const __half* __restrict__ h,
                           const float* __restrict__ ssrc, const float* __restrict__ sdst,
                           const float* __restrict__ bias, OT* __restrict__ out) {
    constexpr int F = HEADS * D;       // 128 or 64
    constexpr int EPL = F / 64;        // elements per lane: 2 or 1
    int lane = threadIdx.x & 63;
    int node = blockIdx.x * (256 / 64) + (threadIdx.x >> 6);
    node = __builtin_amdgcn_readfirstlane(node);
    if (node >= N_NODES) return;
    int hd = lane >> 3;                // head owning this lane's slice

    float sdv = sdst[node * HEADS + hd];
    // self-loop contribution
    float sc0 = ssrc[node * HEADS + hd] + sdv;
    float w0 = __expf(sc0 > 0.f ? sc0 : NEG_SLOPE * sc0);
    float wsum = w0;

    float accx, accy = 0.f;
    if constexpr (EPL == 2) {
        float2 v = __half22float2(*(const __half2*)(h + (long)node * F + lane * 2));
        accx = w0 * v.x; accy = w0 * v.y;
    } else {
        accx = w0 * __half2float(h[(long)node * F + lane]);
    }

    int e0 = rs[node], e1 = rs[node + 1];

    // ---- predicated unroll-by-8: 8 independent gather chains in flight ----
    for (int e = e0; e < e1; e += 8) {
        int sE[8];
#pragma unroll
        for (int i = 0; i < 8; ++i) {
            int idx = e + i;
            int ci = idx < e1 ? idx : e1 - 1;   // clamp: address stays valid
            sE[i] = eidx[ci];
        }
        if constexpr (EPL == 2) {
            __half2 vE[8];
#pragma unroll
            for (int i = 0; i < 8; ++i)
                vE[i] = *(const __half2*)(h + (long)sE[i] * F + lane * 2);
            float wE[8];
#pragma unroll
            for (int i = 0; i < 8; ++i) {
                float sc = ssrc[sE[i] * HEADS + hd] + sdv;
                float w = __expf(sc > 0.f ? sc : NEG_SLOPE * sc);
                wE[i] = (e + i < e1) ? w : 0.f;   // kill tail slots
                wsum += wE[i];
            }
#pragma unroll
            for (int i = 0; i < 8; ++i) {
                float2 v = __half22float2(vE[i]);
                accx = fmaf(wE[i], v.x, accx);
                accy = fmaf(wE[i], v.y, accy);
            }
        } else {
            __half vE[8];
#pragma unroll
            for (int i = 0; i < 8; ++i)
                vE[i] = h[(long)sE[i] * F + lane];
            float wE[8];
#pragma unroll
            for (int i = 0; i < 8; ++i) {
                float sc = ssrc[sE[i] * HEADS + hd] + sdv;
                float w = __expf(sc > 0.f ? sc : NEG_SLOPE * sc);
                wE[i] = (e + i < e1) ? w : 0.f;
                wsum += wE[i];
            }
#pragma unroll
            for (int i = 0; i < 8; ++i)
                accx = fmaf(wE[i], __half2float(vE[i]), accx);
        }
    }

    float inv = 1.f / (wsum + 1e-16f);
    if constexpr (EPL == 2) {
        float2 b = *(const float2*)(bias + lane * 2);
        float ox = accx * inv + b.x;
        float oy = accy * inv + b.y;
        if (RELU) { ox = fmaxf(ox, 0.f); oy = fmaxf(oy, 0.f); }
        if constexpr (sizeof(OT) == 2) {
            *(__half2*)((__half*)out + (long)node * F + lane * 2) = __floats2half2_rn(ox, oy);
        } else {
            *(float2*)((float*)out + (long)node * F + lane * 2) = make_float2(ox, oy);
        }
    } else {
        float o = accx * inv + bias[lane];
        if (RELU) o = fmaxf(o, 0.f);
        if constexpr (sizeof(OT) == 2) {
            ((__half*)out)[(long)node * F + lane] = __float2half(o);
        } else {
            ((float*)out)[(long)node * F + lane] = o;
        }
    }
}

extern "C" void kernel_launch(void* const* d_in, const int* in_sizes, int n_in,
                              void* d_out, int out_size, void* d_ws, size_t ws_size,
                              hipStream_t stream) {
    const float* x   = (const float*)d_in[0];
    const int*   ei  = (const int*)d_in[1];      // [2, N_EDGES] row-major
    const float* W1  = (const float*)d_in[2];
    const float* a1s = (const float*)d_in[3];
    const float* a1d = (const float*)d_in[4];
    const float* b1  = (const float*)d_in[5];
    const float* W2  = (const float*)d_in[6];
    const float* a2s = (const float*)d_in[7];
    const float* a2d = (const float*)d_in[8];
    const float* b2  = (const float*)d_in[9];
    float* out = (float*)d_out;

    const int* src = ei;
    const int* dst = ei + N_EDGES;

    // ---- workspace layout ----
    float* ws = (float*)d_ws;
    float* bufA = ws;                                  // N*128 f32 slot: h1/h2 (fp16)
    float* bufB = bufA + (size_t)N_NODES * 128;        // N*128 f32 slot, time-shared:
                                                       //   bpairs (CSR) -> xh -> h1out
    float* ssrc = bufB + (size_t)N_NODES * 128;        // N*8
    float* sdst = ssrc + (size_t)N_NODES * HEADS;      // N*8
    int* counts    = (int*)(sdst + (size_t)N_NODES * HEADS);  // N ints (carved below)
    int* row_start = counts + N_NODES;                 // N+1
    int* cursor    = row_start + N_NODES + 1;          // N (unused, layout compat)
    int* bsums     = cursor + N_NODES;                 // 128 (unused)
    int* eidx      = bsums + 128;                      // N_EDGES

    int* ghist   = counts;                   // NBKT
    int* bstart  = counts + 512;             // NBKT+1
    int* bcursor = counts + 1024;            // NBKT
    __half* Wt1  = (__half*)(counts + 2048); // 128*128 halves = 8192 ints
    __half* Wt2  = (__half*)(counts + 2048 + 8192);  // 64*128 halves = 4096 ints
    int2* bpairs = (int2*)bufB;              // E*8B; dead before convert_x
    __half* xh    = (__half*)bufB;           // N*128 fp16; dead after gemm1
    __half* h1out = (__half*)bufB;           // N*128 fp16; written by agg L1

    __half* hbuf = (__half*)bufA;

    // ---- CSR build (bucketed two-phase; shared by both layers) ----
    hipMemsetAsync(ghist, 0, NBKT * sizeof(int), stream);
    hist_kernel<<<(N_EDGES + 2047) / 2048, 256, 0, stream>>>(dst, ghist);
    bscan_kernel<<<1, 512, 0, stream>>>(ghist, bstart, bcursor);
    partition_kernel<<<(N_EDGES + PART_CHUNK - 1) / PART_CHUNK, 256, 0, stream>>>(
        src, dst, bcursor, bpairs);
    localcsr_kernel<<<NBKT, 256, 0, stream>>>(bstart, bpairs, row_start, eidx);

    // ---- fp16 conversions (bpairs dead after localcsr) ----
    convert_x_kernel<<<(N_NODES * IN_DIM / 8 + 255) / 256, 256, 0, stream>>>(x, xh);
    convert_wt_kernel<<<(128 * 128 + 255) / 256, 256, 0, stream>>>(W1, Wt1, 128, 128);
    convert_wt_kernel<<<(128 * 64 + 255) / 256, 256, 0, stream>>>(W2, Wt2, 128, 64);

    // ---- Layer 1 ----
    gemm_mfma_kernel<128><<<(N_NODES + 63) / 64, 256, 0, stream>>>(xh, Wt1, hbuf, N_NODES);
    scores_kernel<D1><<<(N_NODES * HEADS + 255) / 256, 256, 0, stream>>>(hbuf, a1s, a1d, ssrc, sdst);
    aggregate_wave_kernel<D1, true, __half><<<(N_NODES + 3) / 4, 256, 0, stream>>>(
        row_start, eidx, hbuf, ssrc, sdst, b1, h1out);

    // ---- Layer 2 ----
    gemm_mfma_kernel<64><<<(N_NODES + 63) / 64, 256, 0, stream>>>(h1out, Wt2, hbuf, N_NODES);
    scores_kernel<D2><<<(N_NODES * HEADS + 255) / 256, 256, 0, stream>>>(hbuf, a2s, a2d, ssrc, sdst);
    aggregate_wave_kernel<D2, false, float><<<(N_NODES + 3) / 4, 256, 0, stream>>>(
        row_start, eidx, hbuf, ssrc, sdst, b2, out);
}